// Round 8
// baseline (269.019 us; speedup 1.0000x reference)
//
#include <hip/hip_runtime.h>
#include <hip/hip_bf16.h>

// PrototypeConsistentLearning: loss = mean(-pos + lse_neg), new_protos = serial EMA.
// B=8192, D=512, K=16384, T=0.5, momentum=0.9.
// R8: flash was LDS-read-pipe-bound (8192 ds_read/CU x 16cyc = 131k cyc vs MFMA 70k).
// (a) B fragments now load global->registers directly (L1/L2-served, no barrier);
// (b) wave tile 128x64 (m=8,n=4 of 16x16x128 fp8 tiles), block 256x128 — A-reads
// amortized 2x; (c) A double-buffered in LDS (2x32KB), ONE __syncthreads per
// chunk-iter; af reads phased in pairs to cap live regs (~235 total, 2 waves/SIMD).
// Tail: loss fused into tail_kernel with ema_apply; 4 launches total.

#define B_N 8192
#define D_N 512
#define K_N 16384
#define INV_T 2.0f
#define MOM 0.9f

#define BM 256
#define BN 128
#define SPLIT 32
#define CAP 64

typedef __attribute__((ext_vector_type(8))) int intx8;
typedef __attribute__((ext_vector_type(4))) float floatx4;

__device__ __forceinline__ void gl_lds16(const void* g, void* lds) {
    __builtin_amdgcn_global_load_lds(
        (const __attribute__((address_space(1))) void*)g,
        (__attribute__((address_space(3))) void*)lds, 16, 0, 0);
}

// ---- head: normalize->fp8 (x16, e4m3) for emb+pro, pos[b] fp32, zero everything ----
__global__ void head_kernel(const float* __restrict__ emb, const float* __restrict__ pro,
                            const int* __restrict__ cid,
                            unsigned char* __restrict__ embq, unsigned char* __restrict__ proq,
                            float* __restrict__ rowpos, float* __restrict__ rowsum,
                            float* __restrict__ out, int* __restrict__ cnt) {
    int bx = blockIdx.x;
    int t = threadIdx.x;
    int lane = t & 63;
    if (bx < (B_N + K_N) / 4) {
        if (bx < 32) rowsum[bx * 256 + t] = 0.0f;
        if (bx == 32 && t == 0) out[0] = 0.0f;
        int row = bx * 4 + (t >> 6);
        const float* x;
        unsigned char* o;
        if (row < B_N) {
            x = emb + (size_t)row * D_N;
            o = embq + (size_t)row * D_N;
        } else {
            x = pro + (size_t)(row - B_N) * D_N;
            o = proq + (size_t)(row - B_N) * D_N;
        }
        const float4* xp = (const float4*)(x + lane * 8);
        float4 v0 = xp[0];
        float4 v1 = xp[1];
        float ss = v0.x * v0.x + v0.y * v0.y + v0.z * v0.z + v0.w * v0.w +
                   v1.x * v1.x + v1.y * v1.y + v1.z * v1.z + v1.w * v1.w;
        #pragma unroll
        for (int of = 32; of; of >>= 1) ss += __shfl_xor(ss, of);
        float sc = 16.0f / fmaxf(sqrtf(ss), 1e-12f);
        int w0 = 0, w1 = 0;
        w0 = __builtin_amdgcn_cvt_pk_fp8_f32(v0.x * sc, v0.y * sc, w0, false);
        w0 = __builtin_amdgcn_cvt_pk_fp8_f32(v0.z * sc, v0.w * sc, w0, true);
        w1 = __builtin_amdgcn_cvt_pk_fp8_f32(v1.x * sc, v1.y * sc, w1, false);
        w1 = __builtin_amdgcn_cvt_pk_fp8_f32(v1.z * sc, v1.w * sc, w1, true);
        int2 st = {w0, w1};
        *(int2*)(o + lane * 8) = st;
    } else {
        int pb = bx - (B_N + K_N) / 4;
        if (t < 8) cnt[pb * 8 + t] = 0;
        int b = pb * 4 + (t >> 6);
        int c = cid[b];
        const float4* ep = (const float4*)(emb + (size_t)b * D_N + lane * 8);
        const float4* pp = (const float4*)(pro + (size_t)c * D_N + lane * 8);
        float4 e0 = ep[0], e1 = ep[1], p0 = pp[0], p1 = pp[1];
        float dp = e0.x * p0.x + e0.y * p0.y + e0.z * p0.z + e0.w * p0.w +
                   e1.x * p1.x + e1.y * p1.y + e1.z * p1.z + e1.w * p1.w;
        float ee = e0.x * e0.x + e0.y * e0.y + e0.z * e0.z + e0.w * e0.w +
                   e1.x * e1.x + e1.y * e1.y + e1.z * e1.z + e1.w * e1.w;
        float qq = p0.x * p0.x + p0.y * p0.y + p0.z * p0.z + p0.w * p0.w +
                   p1.x * p1.x + p1.y * p1.y + p1.z * p1.z + p1.w * p1.w;
        #pragma unroll
        for (int o = 32; o; o >>= 1) {
            dp += __shfl_xor(dp, o);
            ee += __shfl_xor(ee, o);
            qq += __shfl_xor(qq, o);
        }
        if (lane == 0)
            rowpos[b] = INV_T * dp / (fmaxf(sqrtf(ee), 1e-12f) * fmaxf(sqrtf(qq), 1e-12f));
    }
}

// ---- flash GEMM (MX-fp8 16x16x128): rowsum[b] += sum_k exp(2*dot) ----
// Block 256x128, 4 waves of 128x64 (mt 0..7, nt 0..3). A staged via LDS dbuf
// (swizzle slot = granule ^ (row&7), 128-B rows); B fragments direct from global.
__global__ __launch_bounds__(256) void flash_kernel(const unsigned char* __restrict__ embq,
                                                    const unsigned char* __restrict__ proq,
                                                    float* __restrict__ rowsum_g) {
    __shared__ __align__(16) unsigned char As[2][BM * 128];  // 2 x 32 KB
    const int t = threadIdx.x;
    const int w = t >> 6, lane = t & 63;
    const int quad = lane >> 4, lcol = lane & 15;
    const int wm = w >> 1, wn = w & 1;
    const int rowBase = blockIdx.x * BM;
    const int nBegin = blockIdx.y * (K_N / SPLIT);

    // A staging: flat granule f = p*256 + t -> row (f>>3), slot f&7 holds source
    // granule (f&7)^(row&7). (row&7) == ((t>>3)&7) since p*32 = 0 mod 8.
    const int srow = t >> 3;
    const int sG = ((t & 7) ^ (srow & 7)) << 4;
    const unsigned char* aSrc = embq + (size_t)(rowBase + srow) * D_N + sG;

    // A fragment: row = wm*128 + mt*16 + lcol; granules 2q,2q+1 at slot g^(lcol&7).
    const int s0 = ((quad << 1) ^ (lcol & 7)) << 4;
    const int s1 = s0 ^ 16;
    const int aRow = (wm * 128 + lcol) * 128;

    // B direct: lane reads proq[nBegin + tile*128 + wn*64 + nt*16 + lcol]
    //                         [ch*128 + quad*32 + {0,16}]
    const unsigned char* bPtr = proq + (size_t)(nBegin + wn * 64 + lcol) * D_N + quad * 32;

    float rowsum[32];
    #pragma unroll
    for (int i = 0; i < 32; i++) rowsum[i] = 0.0f;

    // prefetch A chunk0 -> buf0
    #pragma unroll
    for (int p = 0; p < 8; p++)
        gl_lds16(aSrc + p * 32 * D_N, &As[0][p * 4096 + w * 1024]);

    #pragma unroll
    for (int tile = 0; tile < 4; tile++) {
        floatx4 acc[8][4];
        #pragma unroll
        for (int mt = 0; mt < 8; mt++)
            #pragma unroll
            for (int nt = 0; nt < 4; nt++) {
                floatx4 z = {0.0f, 0.0f, 0.0f, 0.0f};
                acc[mt][nt] = z;
            }
        #pragma unroll
        for (int ch = 0; ch < 4; ch++) {
            const int buf = ch & 1;
            __syncthreads();  // A[buf] writes (issued last iter) drained + visible
            // B fragments straight from global (L1/L2)
            intx8 bf[4];
            #pragma unroll
            for (int nt = 0; nt < 4; nt++) {
                const unsigned char* q =
                    bPtr + tile * (BN * D_N) + nt * (16 * D_N) + ch * 128;
                int4 lo = *(const int4*)(q);
                int4 hi = *(const int4*)(q + 16);
                intx8 v = {lo.x, lo.y, lo.z, lo.w, hi.x, hi.y, hi.z, hi.w};
                bf[nt] = v;
            }
            // A prefetch into the other buffer (next chunk, or next tile's chunk0)
            if (ch < 3) {
                #pragma unroll
                for (int p = 0; p < 8; p++)
                    gl_lds16(aSrc + p * 32 * D_N + (ch + 1) * 128,
                             &As[buf ^ 1][p * 4096 + w * 1024]);
            } else if (tile < 3) {
                #pragma unroll
                for (int p = 0; p < 8; p++)
                    gl_lds16(aSrc + p * 32 * D_N, &As[buf ^ 1][p * 4096 + w * 1024]);
            }
            // phased A reads + MFMA (af pair live at a time)
            #pragma unroll
            for (int ph = 0; ph < 4; ph++) {
                const unsigned char* a0 = &As[buf][aRow + (2 * ph) * 2048];
                const unsigned char* a1 = &As[buf][aRow + (2 * ph + 1) * 2048];
                int4 l0 = *(const int4*)(a0 + s0);
                int4 h0 = *(const int4*)(a0 + s1);
                int4 l1 = *(const int4*)(a1 + s0);
                int4 h1 = *(const int4*)(a1 + s1);
                intx8 af0 = {l0.x, l0.y, l0.z, l0.w, h0.x, h0.y, h0.z, h0.w};
                intx8 af1 = {l1.x, l1.y, l1.z, l1.w, h1.x, h1.y, h1.z, h1.w};
                #pragma unroll
                for (int nt = 0; nt < 4; nt++) {
                    acc[2 * ph][nt] = __builtin_amdgcn_mfma_scale_f32_16x16x128_f8f6f4(
                        af0, bf[nt], acc[2 * ph][nt], 0, 0, 0, 0x7F7F7F7F, 0, 0x7F7F7F7F);
                    acc[2 * ph + 1][nt] = __builtin_amdgcn_mfma_scale_f32_16x16x128_f8f6f4(
                        af1, bf[nt], acc[2 * ph + 1][nt], 0, 0, 0, 0x7F7F7F7F, 0,
                        0x7F7F7F7F);
                }
            }
        }
        // epilogue: C/D col=lcol, row=quad*4+r; unscale (16*16)^-1 = 2^-8
        #pragma unroll
        for (int mt = 0; mt < 8; mt++)
            #pragma unroll
            for (int nt = 0; nt < 4; nt++)
                #pragma unroll
                for (int r = 0; r < 4; r++)
                    rowsum[mt * 4 + r] += __expf(acc[mt][nt][r] * (INV_T / 256.0f));
    }
    #pragma unroll
    for (int i = 0; i < 32; i++) {
        #pragma unroll
        for (int o = 1; o < 16; o <<= 1) rowsum[i] += __shfl_xor(rowsum[i], o);
    }
    if (lcol == 0) {
        #pragma unroll
        for (int mt = 0; mt < 8; mt++)
            #pragma unroll
            for (int r = 0; r < 4; r++)
                atomicAdd(&rowsum_g[rowBase + wm * 128 + mt * 16 + quad * 4 + r],
                          rowsum[mt * 4 + r]);
    }
}

// ---- EMA phase 1: bucket occurrence indices per cluster (cnt zeroed by head). ----
__global__ void ema_count(const int* __restrict__ cid, int* __restrict__ cnt,
                          int* __restrict__ bucket) {
    int b = blockIdx.x * 256 + threadIdx.x;
    int c = cid[b];
    int slot = atomicAdd(&cnt[c], 1);
    if (slot < CAP) bucket[c * CAP + slot] = b;
}

// ---- tail: blocks 0..31 loss partial; blocks 32.. serial-EMA per cluster. ----
__global__ void tail_kernel(const float* __restrict__ rowsum, const float* __restrict__ rowpos,
                            float* __restrict__ out, const float* __restrict__ emb,
                            const float* __restrict__ pro, const int* __restrict__ cnt,
                            const int* __restrict__ bucket, float* __restrict__ outp) {
    int bx = blockIdx.x;
    int t = threadIdx.x;
    if (bx < 32) {
        __shared__ float red[256];
        int b = bx * 256 + t;
        float p = rowpos[b];
        red[t] = logf(rowsum[b] - __expf(p)) - p;
        __syncthreads();
        for (int o = 128; o; o >>= 1) {
            if (t < o) red[t] += red[t + o];
            __syncthreads();
        }
        if (t == 0) atomicAdd(out, red[0] * (1.0f / (float)B_N));
        return;
    }
    int k = (bx - 32) * 4 + (t >> 6);
    int lane = t & 63;
    int n = cnt[k];
    n = n < CAP ? n : CAP;
    const float4* pp = (const float4*)(pro + (size_t)k * D_N + lane * 8);
    float4 a0 = pp[0], a1 = pp[1];
    int myb = (lane < n) ? bucket[k * CAP + lane] : 0x7fffffff;
    for (int i = 0; i < n; i++) {
        int m = myb;
        #pragma unroll
        for (int o = 1; o < 64; o <<= 1) {
            int v = __shfl_xor(m, o);
            m = v < m ? v : m;
        }
        const float4* ep = (const float4*)(emb + (size_t)m * D_N + lane * 8);
        float4 e0 = ep[0], e1 = ep[1];
        a0.x = MOM * a0.x + (1.0f - MOM) * e0.x;
        a0.y = MOM * a0.y + (1.0f - MOM) * e0.y;
        a0.z = MOM * a0.z + (1.0f - MOM) * e0.z;
        a0.w = MOM * a0.w + (1.0f - MOM) * e0.w;
        a1.x = MOM * a1.x + (1.0f - MOM) * e1.x;
        a1.y = MOM * a1.y + (1.0f - MOM) * e1.y;
        a1.z = MOM * a1.z + (1.0f - MOM) * e1.z;
        a1.w = MOM * a1.w + (1.0f - MOM) * e1.w;
        if (myb == m) myb = 0x7fffffff;
    }
    float4* op = (float4*)(outp + (size_t)k * D_N + lane * 8);
    op[0] = a0;
    op[1] = a1;
}

extern "C" void kernel_launch(void* const* d_in, const int* in_sizes, int n_in,
                              void* d_out, int out_size, void* d_ws, size_t ws_size,
                              hipStream_t stream) {
    const float* emb = (const float*)d_in[0];
    const int* cid = (const int*)d_in[1];
    const float* pro = (const float*)d_in[2];
    float* out = (float*)d_out;

    char* ws = (char*)d_ws;
    unsigned char* embq = (unsigned char*)ws;                      // 4 MB fp8 [B,D]
    unsigned char* proq = (unsigned char*)(ws + 4194304);          // 8 MB fp8 [K,D]
    float* rowsum = (float*)(ws + 12582912);                       // [B]
    float* rowpos = (float*)(ws + 12615680);                       // [B]
    int* cnt = (int*)(ws + 12648448);                              // [K]
    int* bucket = (int*)(ws + 12713984);                           // [K, CAP] 4 MB

    head_kernel<<<(B_N + K_N) / 4 + B_N / 4, 256, 0, stream>>>(emb, pro, cid, embq, proq,
                                                               rowpos, rowsum, out, cnt);
    ema_count<<<B_N / 256, 256, 0, stream>>>(cid, cnt, bucket);
    flash_kernel<<<dim3(B_N / BM, SPLIT), 256, 0, stream>>>(embq, proq, rowsum);
    tail_kernel<<<32 + K_N / 4, 256, 0, stream>>>(rowsum, rowpos, out, emb, pro, cnt,
                                                  bucket, out + 1);
}